// Round 5
// baseline (203.505 us; speedup 1.0000x reference)
//
#include <hip/hip_runtime.h>

#define NB 64
#define NT 2048
#define NQD 512
#define NKD 512
#define NVD 512
#define NAD 256

typedef __attribute__((ext_vector_type(8))) short s16x8;
typedef __attribute__((ext_vector_type(4))) float fx4;
typedef __attribute__((ext_vector_type(4))) unsigned int u32x4;

__device__ __forceinline__ short f2bf(float x) {
  union { float f; unsigned u; } v; v.f = x;
  return (short)((v.u + 0x7fffu + ((v.u >> 16) & 1u)) >> 16);  // RNE
}

// 2x f32 -> packed bf16 (lo -> bits[15:0], hi -> bits[31:16])
__device__ __forceinline__ unsigned cvt_pk_bf16(float lo, float hi) {
  unsigned r;
  asm("v_cvt_pk_bf16_f32 %0, %1, %2" : "=v"(r) : "v"(lo), "v"(hi));
  return r;
}

// tanh(x) = 1 - 2/(1+e^{2x});  exact saturation at +/-1, rel err ~1e-7
__device__ __forceinline__ float fast_tanh(float x) {
  float e = __expf(x + x);
  return 1.0f - 2.0f * __builtin_amdgcn_rcpf(e + 1.0f);
}

// convert 16 f32 (4x fx4) -> 32B bf16 granule, write as 2 swizzled 16B chunks
__device__ __forceinline__ void cvt_write32(short* lds, int lbase, int swz, const fx4* q) {
  u32x4 w0, w1;
  w0[0] = cvt_pk_bf16(q[0][0], q[0][1]); w0[1] = cvt_pk_bf16(q[0][2], q[0][3]);
  w0[2] = cvt_pk_bf16(q[1][0], q[1][1]); w0[3] = cvt_pk_bf16(q[1][2], q[1][3]);
  w1[0] = cvt_pk_bf16(q[2][0], q[2][1]); w1[1] = cvt_pk_bf16(q[2][2], q[2][3]);
  w1[2] = cvt_pk_bf16(q[3][0], q[3][1]); w1[3] = cvt_pk_bf16(q[3][2], q[3][3]);
  *(u32x4*)((char*)lds + ((lbase) ^ swz)) = w0;
  *(u32x4*)((char*)lds + ((lbase + 16) ^ swz)) = w1;
}

// ---- kernel 1: fused prep.  blocks 0..63: qpk[b][n] = query[b]·Wq[:,n]+bq+bk
//                             blocks 64..95: WkT[a][k] = bf16(Wk[k][a])
__global__ void prep_kernel(const float* __restrict__ query, const float* __restrict__ Wq,
                            const float* __restrict__ bq, const float* __restrict__ bk,
                            const float* __restrict__ Wk,
                            float* __restrict__ qpk, short* __restrict__ WkT) {
  __shared__ float sm[64][65];
  const int tid = threadIdx.x;
  if (blockIdx.x < NB) {
    const int b = blockIdx.x;
    float* q = &sm[0][0];
    for (int k = tid; k < NQD; k += 256) q[k] = query[b * NQD + k];
    __syncthreads();
    float acc = bq[tid] + bk[tid];
#pragma unroll 8
    for (int k = 0; k < NQD; ++k) acc += q[k] * Wq[k * NAD + tid];
    qpk[b * NAD + tid] = acc;
  } else {
    const int blk = blockIdx.x - NB;
    const int kb = (blk & 7) * 64, ab = (blk >> 3) * 64;
    const int c = tid & 63, r0 = tid >> 6;
#pragma unroll
    for (int rr = r0; rr < 64; rr += 4)
      sm[rr][c] = Wk[(size_t)(kb + rr) * NAD + ab + c];
    __syncthreads();
#pragma unroll
    for (int rr = r0; rr < 64; rr += 4)
      WkT[(size_t)(ab + rr) * NKD + kb + c] = f2bf(sm[c][rr]);
  }
}

// ---- kernel 2: fused GEMM(key@Wk) + tanh + ·Wo reduce -> score[b*T+t]
// BM=64, BK=128 chunks (4 of them), LDS 2x16KB double-buffered (3 blocks/CU).
// A: global->regs early, cvt+swizzled-LDS-write late. B: straight from
// L2-resident WkT, reg-prefetched 1 K-step ahead. 16 MFMA / K-step / wave.
__global__ void __launch_bounds__(256, 3)
score_kernel(const float* __restrict__ key, const short* __restrict__ WkT,
             const float* __restrict__ qpk, const float* __restrict__ Wo,
             float* __restrict__ score) {
  __shared__ short As[2][64 * 128];     // 2 x 16 KB, [row][k] bf16, byte^((row&7)<<4)
  __shared__ float sred[4][64];
  const int tid = threadIdx.x;
  const int w = tid >> 6, l = tid & 63;
  const int g = l >> 4, h = l & 15;
  const int m0 = blockIdx.x * 64;       // 32 blocks/batch; tiles never span batches
  const int b = m0 >> 11;

  const short* bp[4];
#pragma unroll
  for (int nt = 0; nt < 4; ++nt)
    bp[nt] = WkT + (size_t)(w * 64 + nt * 16 + h) * NKD + g * 8;

  // B K-step 0: issue before the staging burst so it lands underneath it
  s16x8 bcur[4];
#pragma unroll
  for (int nt = 0; nt < 4; ++nt) bcur[nt] = *(const s16x8*)bp[nt];

  // staging geometry: thread handles granules (r, kseg) and (r+32, kseg)
  const int r = tid >> 3, kseg = tid & 7;           // 16 k elems per granule
  const float* asrc0 = key + (size_t)(m0 + r) * NKD + kseg * 16;
  const float* asrc1 = asrc0 + (size_t)32 * NKD;
  const int lbase0 = r * 256 + kseg * 32;           // row stride 128k*2B = 256B
  const int lbase1 = lbase0 + 32 * 256;
  const int swz = (r & 7) << 4;

  // prologue: stage chunk 0 into buf 0
  {
    fx4 st[8];
#pragma unroll
    for (int i = 0; i < 4; ++i) st[i] = *(const fx4*)(asrc0 + i * 4);
#pragma unroll
    for (int i = 0; i < 4; ++i) st[4 + i] = *(const fx4*)(asrc1 + i * 4);
    cvt_write32(&As[0][0], lbase0, swz, &st[0]);
    cvt_write32(&As[0][0], lbase1, swz, &st[4]);
  }
  __syncthreads();

  fx4 acc[4][4];
#pragma unroll
  for (int i = 0; i < 4; ++i)
#pragma unroll
    for (int j = 0; j < 4; ++j) acc[i][j] = fx4{0.f, 0.f, 0.f, 0.f};

  const int rsw = (h & 7) << 4;

  int buf = 0;
  for (int c = 0; c < 4; ++c) {
    const bool notLast = (c < 3);
    fx4 st[8];
    if (notLast) {  // T14 issue-early: whole next chunk's loads up front
      const float* gp0 = asrc0 + (c + 1) * 128;
      const float* gp1 = asrc1 + (c + 1) * 128;
#pragma unroll
      for (int i = 0; i < 4; ++i) st[i] = *(const fx4*)(gp0 + i * 4);
#pragma unroll
      for (int i = 0; i < 4; ++i) st[4 + i] = *(const fx4*)(gp1 + i * 4);
    }
#pragma unroll
    for (int kl = 0; kl < 4; ++kl) {
      const int ks = c * 4 + kl;
      s16x8 bnxt[4];
      if (ks < 15) {
#pragma unroll
        for (int nt = 0; nt < 4; ++nt)
          bnxt[nt] = *(const s16x8*)(bp[nt] + (ks + 1) * 32);
      }
      s16x8 af[4];
#pragma unroll
      for (int mt = 0; mt < 4; ++mt)
        af[mt] = *(const s16x8*)((const char*)&As[buf][0] +
                                 (((mt * 16 + h) * 256 + kl * 64 + g * 16) ^ rsw));
#pragma unroll
      for (int mt = 0; mt < 4; ++mt)
#pragma unroll
        for (int nt = 0; nt < 4; ++nt)
          acc[mt][nt] = __builtin_amdgcn_mfma_f32_16x16x32_bf16(af[mt], bcur[nt], acc[mt][nt], 0, 0, 0);
      if (ks < 15) {
#pragma unroll
        for (int nt = 0; nt < 4; ++nt) bcur[nt] = bnxt[nt];
      }
    }
    if (notLast) {  // T14 write-late
      cvt_write32(&As[buf ^ 1][0], lbase0, swz, &st[0]);
      cvt_write32(&As[buf ^ 1][0], lbase1, swz, &st[4]);
    }
    __syncthreads();
    buf ^= 1;
  }

  // epilogue: score row m = m0 + mt*16 + 4g + reg  (C layout col=h, row=4g+reg)
  float qv[4], wv[4];
#pragma unroll
  for (int nt = 0; nt < 4; ++nt) {
    const int n = w * 64 + nt * 16 + h;
    qv[nt] = qpk[b * NAD + n];
    wv[nt] = Wo[n];
  }
#pragma unroll
  for (int mt = 0; mt < 4; ++mt) {
#pragma unroll
    for (int rr = 0; rr < 4; ++rr) {
      float s = fast_tanh(acc[mt][0][rr] + qv[0]) * wv[0]
              + fast_tanh(acc[mt][1][rr] + qv[1]) * wv[1]
              + fast_tanh(acc[mt][2][rr] + qv[2]) * wv[2]
              + fast_tanh(acc[mt][3][rr] + qv[3]) * wv[3];
#pragma unroll
      for (int off = 1; off < 16; off <<= 1) s += __shfl_xor(s, off, 64);
      if (h == 0) sred[w][mt * 16 + g * 4 + rr] = s;
    }
  }
  __syncthreads();
  if (tid < 64)
    score[m0 + tid] = sred[0][tid] + sred[1][tid] + sred[2][tid] + sred[3][tid];
}

// ---- kernel 3: softmax over T per batch (bo dropped: softmax shift-invariant)
__global__ void softmax_kernel(const float* __restrict__ score, float* __restrict__ attn) {
  __shared__ float redm[4];
  __shared__ float reds[4];
  const int b = blockIdx.x, tid = threadIdx.x;
  const float* s = score + (size_t)b * NT;
  float v[8];
  float m = -3.0e38f;
#pragma unroll
  for (int j = 0; j < 8; ++j) { v[j] = s[tid + j * 256]; m = fmaxf(m, v[j]); }
#pragma unroll
  for (int off = 1; off < 64; off <<= 1) m = fmaxf(m, __shfl_xor(m, off, 64));
  if ((tid & 63) == 0) redm[tid >> 6] = m;
  __syncthreads();
  m = fmaxf(fmaxf(redm[0], redm[1]), fmaxf(redm[2], redm[3]));
  float sum = 0.f;
#pragma unroll
  for (int j = 0; j < 8; ++j) { v[j] = __expf(v[j] - m); sum += v[j]; }
#pragma unroll
  for (int off = 1; off < 64; off <<= 1) sum += __shfl_xor(sum, off, 64);
  if ((tid & 63) == 0) reds[tid >> 6] = sum;
  __syncthreads();
  sum = reds[0] + reds[1] + reds[2] + reds[3];
  const float inv = 1.0f / sum;
#pragma unroll
  for (int j = 0; j < 8; ++j) attn[(size_t)b * NT + tid + j * 256] = v[j] * inv;
}

// ---- kernel 4: partial context over 64-row t-chunks (float4 loads)
__global__ void ctx_partial_kernel(const float* __restrict__ attn, const float* __restrict__ value,
                                   float* __restrict__ partial) {
  __shared__ float a[64];
  __shared__ fx4 red[128];
  const int blk = blockIdx.x;       // b*32 + tc
  const int b = blk >> 5, tc = blk & 31;
  const int tid = threadIdx.x;
  if (tid < 64) a[tid] = attn[(size_t)b * NT + tc * 64 + tid];
  __syncthreads();
  const int half = tid >> 7;        // 0: even rows, 1: odd rows
  const int vi = (tid & 127) * 4;   // 128 threads cover VD=512
  const float* vp = value + ((size_t)b * NT + tc * 64 + half) * NVD + vi;
  fx4 s = fx4{0.f, 0.f, 0.f, 0.f};
#pragma unroll 8
  for (int t = 0; t < 64; t += 2) {
    fx4 x = *(const fx4*)(vp + (size_t)t * NVD);
    const float wt = a[t + half];
    s += x * wt;
  }
  if (half) red[tid & 127] = s;
  __syncthreads();
  if (!half) {
    s += red[tid];
    *(fx4*)(partial + (size_t)blk * NVD + vi) = s;
  }
}

// ---- kernel 5: reduce partials -> context
__global__ void ctx_reduce_kernel(const float* __restrict__ partial, float* __restrict__ ctx) {
  const int i = blockIdx.x * 256 + threadIdx.x;  // < NB*NVD
  const int b = i >> 9, v = i & (NVD - 1);
  float s = 0.f;
#pragma unroll
  for (int tc = 0; tc < 32; ++tc) s += partial[(size_t)(b * 32 + tc) * NVD + v];
  ctx[i] = s;
}

extern "C" void kernel_launch(void* const* d_in, const int* in_sizes, int n_in,
                              void* d_out, int out_size, void* d_ws, size_t ws_size,
                              hipStream_t stream) {
  const float* query = (const float*)d_in[0];
  const float* key   = (const float*)d_in[1];
  const float* value = (const float*)d_in[2];
  const float* Wq    = (const float*)d_in[3];
  const float* bq    = (const float*)d_in[4];
  const float* Wk    = (const float*)d_in[5];
  const float* bk    = (const float*)d_in[6];
  const float* Wo    = (const float*)d_in[7];
  // d_in[8] = bo: unused — softmax over T is invariant to a uniform shift.

  float* out  = (float*)d_out;
  float* ctx  = out;                // [B][VD]
  float* attn = out + NB * NVD;     // [B][T]

  char* ws = (char*)d_ws;
  float* qpk     = (float*)(ws);                                   // 64 KB
  short* WkT     = (short*)(ws + 64 * 1024);                       // 256 KB
  float* score   = (float*)(ws + (64 + 256) * 1024);               // 512 KB
  float* partial = (float*)(ws + (64 + 256 + 512) * 1024);         // 4 MB

  prep_kernel<<<NB + 32, 256, 0, stream>>>(query, Wq, bq, bk, Wk, qpk, WkT);
  score_kernel<<<(NB * NT) / 64, 256, 0, stream>>>(key, WkT, qpk, Wo, score);
  softmax_kernel<<<NB, 256, 0, stream>>>(score, attn);
  ctx_partial_kernel<<<NB * 32, 256, 0, stream>>>(attn, value, partial);
  ctx_reduce_kernel<<<(NB * NVD) / 256, 256, 0, stream>>>(partial, ctx);
}

// Round 6
// 170.738 us; speedup vs baseline: 1.1919x; 1.1919x over previous
//
#include <hip/hip_runtime.h>

#define NB 64
#define NT 2048
#define NQD 512
#define NKD 512
#define NVD 512
#define NAD 256

typedef __attribute__((ext_vector_type(8))) short s16x8;
typedef __attribute__((ext_vector_type(4))) float fx4;
typedef __attribute__((ext_vector_type(4))) unsigned int u32x4;

__device__ __forceinline__ short f2bf(float x) {
  union { float f; unsigned u; } v; v.f = x;
  return (short)((v.u + 0x7fffu + ((v.u >> 16) & 1u)) >> 16);  // RNE
}

// 2x f32 -> packed bf16 (lo -> bits[15:0], hi -> bits[31:16])
__device__ __forceinline__ unsigned cvt_pk_bf16(float lo, float hi) {
  unsigned r;
  asm("v_cvt_pk_bf16_f32 %0, %1, %2" : "=v"(r) : "v"(lo), "v"(hi));
  return r;
}

// tanh(x) = 1 - 2/(1+e^{2x});  exact saturation at +/-1, rel err ~1e-7
__device__ __forceinline__ float fast_tanh(float x) {
  float e = __expf(x + x);
  return 1.0f - 2.0f * __builtin_amdgcn_rcpf(e + 1.0f);
}

// convert 16 f32 (4x fx4) -> 32B bf16 granule, write as 2 swizzled 16B chunks
__device__ __forceinline__ void cvt_write32(short* lds, int lbase, int swz, const fx4* q) {
  u32x4 w0, w1;
  w0[0] = cvt_pk_bf16(q[0][0], q[0][1]); w0[1] = cvt_pk_bf16(q[0][2], q[0][3]);
  w0[2] = cvt_pk_bf16(q[1][0], q[1][1]); w0[3] = cvt_pk_bf16(q[1][2], q[1][3]);
  w1[0] = cvt_pk_bf16(q[2][0], q[2][1]); w1[1] = cvt_pk_bf16(q[2][2], q[2][3]);
  w1[2] = cvt_pk_bf16(q[3][0], q[3][1]); w1[3] = cvt_pk_bf16(q[3][2], q[3][3]);
  *(u32x4*)((char*)lds + ((lbase) ^ swz)) = w0;
  *(u32x4*)((char*)lds + ((lbase + 16) ^ swz)) = w1;
}

// ---- kernel 1: fused prep.
// blocks 0..63:  qpk[b][n] = query[b]·Wq[:,n] + bq[n] + bk[n]
// blocks 64..79: Bpk = Wk as bf16 packed in MFMA B-fragment lane order:
//   Bpk[(ks*1024 + wnt*64 + g*16 + h)*8 + j] = bf16(Wk[ks*32+g*8+j][wnt*16+h])
//   so a wave's fragment load is one fully-coalesced 1KB request.
__global__ void prep_kernel(const float* __restrict__ query, const float* __restrict__ Wq,
                            const float* __restrict__ bq, const float* __restrict__ bk,
                            const float* __restrict__ Wk,
                            float* __restrict__ qpk, short* __restrict__ Bpk) {
  __shared__ float q[NQD];
  const int tid = threadIdx.x;
  if (blockIdx.x < NB) {
    const int b = blockIdx.x;
    for (int k = tid; k < NQD; k += 256) q[k] = query[b * NQD + k];
    __syncthreads();
    float acc = bq[tid] + bk[tid];
#pragma unroll 8
    for (int k = 0; k < NQD; ++k) acc += q[k] * Wq[k * NAD + tid];
    qpk[b * NAD + tid] = acc;
  } else {
    const int ks = blockIdx.x - NB;          // 0..15 (K-step)
#pragma unroll
    for (int rep = 0; rep < 4; ++rep) {
      const int o = rep * 256 + tid;         // chunk id within ks: 0..1023
      const int wnt = o >> 6;                // w*4+nt (0..15)
      const int l = o & 63;
      const int g = l >> 4, h = l & 15;
      const int n = wnt * 16 + h;            // == w*64 + nt*16 + h
      const int k0 = ks * 32 + g * 8;
      s16x8 v;
#pragma unroll
      for (int j = 0; j < 8; ++j) v[j] = f2bf(Wk[(size_t)(k0 + j) * NAD + n]);
      *(s16x8*)(Bpk + (size_t)(ks * 1024 + o) * 8) = v;  // 16B coalesced
    }
  }
}

// ---- kernel 2: fused GEMM(key@Wk) + tanh + ·Wo reduce -> score[b*T+t]
// BM=64, BK=128 chunks (4), LDS 2x16KB dbuf (3 blocks/CU). A: global->regs
// early, cvt+swizzled-LDS-write late. B: coalesced fragment loads from Bpk
// (L2-resident), reg-prefetched 1 K-step ahead. 16 MFMA / K-step / wave.
__global__ void __launch_bounds__(256, 3)
score_kernel(const float* __restrict__ key, const short* __restrict__ Bpk,
             const float* __restrict__ qpk, const float* __restrict__ Wo,
             float* __restrict__ score) {
  __shared__ short As[2][64 * 128];     // 2 x 16 KB, [row][k] bf16, byte^((row&7)<<4)
  __shared__ float sred[4][64];
  const int tid = threadIdx.x;
  const int w = tid >> 6, l = tid & 63;
  const int g = l >> 4, h = l & 15;
  const int m0 = blockIdx.x * 64;       // 32 blocks/batch; tiles never span batches
  const int b = m0 >> 11;

  // B fragment base for this thread: nt-panels are 1KB apart, K-steps 8KB apart
  const short* bbase = Bpk + (size_t)(w * 4 * 64 + l) * 8;

  // B K-step 0: issue before the staging burst so it lands underneath it
  s16x8 bcur[4];
#pragma unroll
  for (int nt = 0; nt < 4; ++nt) bcur[nt] = *(const s16x8*)(bbase + nt * 512);

  // staging geometry: thread handles granules (r, kseg) and (r+32, kseg)
  const int r = tid >> 3, kseg = tid & 7;           // 16 k elems per granule
  const float* asrc0 = key + (size_t)(m0 + r) * NKD + kseg * 16;
  const float* asrc1 = asrc0 + (size_t)32 * NKD;
  const int lbase0 = r * 256 + kseg * 32;           // row stride 128k*2B = 256B
  const int lbase1 = lbase0 + 32 * 256;
  const int swz = (r & 7) << 4;

  // prologue: stage chunk 0 into buf 0
  {
    fx4 st[8];
#pragma unroll
    for (int i = 0; i < 4; ++i) st[i] = *(const fx4*)(asrc0 + i * 4);
#pragma unroll
    for (int i = 0; i < 4; ++i) st[4 + i] = *(const fx4*)(asrc1 + i * 4);
    cvt_write32(&As[0][0], lbase0, swz, &st[0]);
    cvt_write32(&As[0][0], lbase1, swz, &st[4]);
  }
  __syncthreads();

  fx4 acc[4][4];
#pragma unroll
  for (int i = 0; i < 4; ++i)
#pragma unroll
    for (int j = 0; j < 4; ++j) acc[i][j] = fx4{0.f, 0.f, 0.f, 0.f};

  const int rsw = (h & 7) << 4;

  int buf = 0;
  for (int c = 0; c < 4; ++c) {
    const bool notLast = (c < 3);
    fx4 st[8];
    if (notLast) {  // T14 issue-early: whole next chunk's loads up front
      const float* gp0 = asrc0 + (c + 1) * 128;
      const float* gp1 = asrc1 + (c + 1) * 128;
#pragma unroll
      for (int i = 0; i < 4; ++i) st[i] = *(const fx4*)(gp0 + i * 4);
#pragma unroll
      for (int i = 0; i < 4; ++i) st[4 + i] = *(const fx4*)(gp1 + i * 4);
    }
#pragma unroll
    for (int kl = 0; kl < 4; ++kl) {
      const int ks = c * 4 + kl;
      s16x8 bnxt[4];
      if (ks < 15) {
#pragma unroll
        for (int nt = 0; nt < 4; ++nt)
          bnxt[nt] = *(const s16x8*)(bbase + (size_t)(ks + 1) * 8192 + nt * 512);
      }
      s16x8 af[4];
#pragma unroll
      for (int mt = 0; mt < 4; ++mt)
        af[mt] = *(const s16x8*)((const char*)&As[buf][0] +
                                 (((mt * 16 + h) * 256 + kl * 64 + g * 16) ^ rsw));
#pragma unroll
      for (int mt = 0; mt < 4; ++mt)
#pragma unroll
        for (int nt = 0; nt < 4; ++nt)
          acc[mt][nt] = __builtin_amdgcn_mfma_f32_16x16x32_bf16(af[mt], bcur[nt], acc[mt][nt], 0, 0, 0);
      if (ks < 15) {
#pragma unroll
        for (int nt = 0; nt < 4; ++nt) bcur[nt] = bnxt[nt];
      }
    }
    if (notLast) {  // T14 write-late
      cvt_write32(&As[buf ^ 1][0], lbase0, swz, &st[0]);
      cvt_write32(&As[buf ^ 1][0], lbase1, swz, &st[4]);
    }
    __syncthreads();
    buf ^= 1;
  }

  // epilogue: score row m = m0 + mt*16 + 4g + reg  (C layout col=h, row=4g+reg)
  float qv[4], wv[4];
#pragma unroll
  for (int nt = 0; nt < 4; ++nt) {
    const int n = w * 64 + nt * 16 + h;
    qv[nt] = qpk[b * NAD + n];
    wv[nt] = Wo[n];
  }
#pragma unroll
  for (int mt = 0; mt < 4; ++mt) {
#pragma unroll
    for (int rr = 0; rr < 4; ++rr) {
      float s = fast_tanh(acc[mt][0][rr] + qv[0]) * wv[0]
              + fast_tanh(acc[mt][1][rr] + qv[1]) * wv[1]
              + fast_tanh(acc[mt][2][rr] + qv[2]) * wv[2]
              + fast_tanh(acc[mt][3][rr] + qv[3]) * wv[3];
#pragma unroll
      for (int off = 1; off < 16; off <<= 1) s += __shfl_xor(s, off, 64);
      if (h == 0) sred[w][mt * 16 + g * 4 + rr] = s;
    }
  }
  __syncthreads();
  if (tid < 64)
    score[m0 + tid] = sred[0][tid] + sred[1][tid] + sred[2][tid] + sred[3][tid];
}

// ---- kernel 3: softmax over T per batch (bo dropped: softmax shift-invariant)
__global__ void softmax_kernel(const float* __restrict__ score, float* __restrict__ attn) {
  __shared__ float redm[4];
  __shared__ float reds[4];
  const int b = blockIdx.x, tid = threadIdx.x;
  const float* s = score + (size_t)b * NT;
  float v[8];
  float m = -3.0e38f;
#pragma unroll
  for (int j = 0; j < 8; ++j) { v[j] = s[tid + j * 256]; m = fmaxf(m, v[j]); }
#pragma unroll
  for (int off = 1; off < 64; off <<= 1) m = fmaxf(m, __shfl_xor(m, off, 64));
  if ((tid & 63) == 0) redm[tid >> 6] = m;
  __syncthreads();
  m = fmaxf(fmaxf(redm[0], redm[1]), fmaxf(redm[2], redm[3]));
  float sum = 0.f;
#pragma unroll
  for (int j = 0; j < 8; ++j) { v[j] = __expf(v[j] - m); sum += v[j]; }
#pragma unroll
  for (int off = 1; off < 64; off <<= 1) sum += __shfl_xor(sum, off, 64);
  if ((tid & 63) == 0) reds[tid >> 6] = sum;
  __syncthreads();
  sum = reds[0] + reds[1] + reds[2] + reds[3];
  const float inv = 1.0f / sum;
#pragma unroll
  for (int j = 0; j < 8; ++j) attn[(size_t)b * NT + tid + j * 256] = v[j] * inv;
}

// ---- kernel 4: partial context over 64-row t-chunks (float4 loads)
__global__ void ctx_partial_kernel(const float* __restrict__ attn, const float* __restrict__ value,
                                   float* __restrict__ partial) {
  __shared__ float a[64];
  __shared__ fx4 red[128];
  const int blk = blockIdx.x;       // b*32 + tc
  const int b = blk >> 5, tc = blk & 31;
  const int tid = threadIdx.x;
  if (tid < 64) a[tid] = attn[(size_t)b * NT + tc * 64 + tid];
  __syncthreads();
  const int half = tid >> 7;        // 0: even rows, 1: odd rows
  const int vi = (tid & 127) * 4;   // 128 threads cover VD=512
  const float* vp = value + ((size_t)b * NT + tc * 64 + half) * NVD + vi;
  fx4 s = fx4{0.f, 0.f, 0.f, 0.f};
#pragma unroll 8
  for (int t = 0; t < 64; t += 2) {
    fx4 x = *(const fx4*)(vp + (size_t)t * NVD);
    const float wt = a[t + half];
    s += x * wt;
  }
  if (half) red[tid & 127] = s;
  __syncthreads();
  if (!half) {
    s += red[tid];
    *(fx4*)(partial + (size_t)blk * NVD + vi) = s;
  }
}

// ---- kernel 5: reduce partials -> context
__global__ void ctx_reduce_kernel(const float* __restrict__ partial, float* __restrict__ ctx) {
  const int i = blockIdx.x * 256 + threadIdx.x;  // < NB*NVD
  const int b = i >> 9, v = i & (NVD - 1);
  float s = 0.f;
#pragma unroll
  for (int tc = 0; tc < 32; ++tc) s += partial[(size_t)(b * 32 + tc) * NVD + v];
  ctx[i] = s;
}

extern "C" void kernel_launch(void* const* d_in, const int* in_sizes, int n_in,
                              void* d_out, int out_size, void* d_ws, size_t ws_size,
                              hipStream_t stream) {
  const float* query = (const float*)d_in[0];
  const float* key   = (const float*)d_in[1];
  const float* value = (const float*)d_in[2];
  const float* Wq    = (const float*)d_in[3];
  const float* bq    = (const float*)d_in[4];
  const float* Wk    = (const float*)d_in[5];
  const float* bk    = (const float*)d_in[6];
  const float* Wo    = (const float*)d_in[7];
  // d_in[8] = bo: unused — softmax over T is invariant to a uniform shift.

  float* out  = (float*)d_out;
  float* ctx  = out;                // [B][VD]
  float* attn = out + NB * NVD;     // [B][T]

  char* ws = (char*)d_ws;
  float* qpk     = (float*)(ws);                                   // 64 KB
  short* Bpk     = (short*)(ws + 64 * 1024);                       // 256 KB
  float* score   = (float*)(ws + (64 + 256) * 1024);               // 512 KB
  float* partial = (float*)(ws + (64 + 256 + 512) * 1024);         // 4 MB

  prep_kernel<<<NB + 16, 256, 0, stream>>>(query, Wq, bq, bk, Wk, qpk, Bpk);
  score_kernel<<<(NB * NT) / 64, 256, 0, stream>>>(key, Bpk, qpk, Wo, score);
  softmax_kernel<<<NB, 256, 0, stream>>>(score, attn);
  ctx_partial_kernel<<<NB * 32, 256, 0, stream>>>(attn, value, partial);
  ctx_reduce_kernel<<<(NB * NVD) / 256, 256, 0, stream>>>(partial, ctx);
}